// Round 1
// 543.319 us; speedup vs baseline: 1.0014x; 1.0014x over previous
//
#include <hip/hip_runtime.h>

// Problem constants (from reference): inputs (16, 512, 64, 192) fp32
constexpr int Bq = 16;
constexpr int Cc = 256;          // channels per half (x1 / x2)
constexpr int Hh = 64;
constexpr int Ww = 192;
constexpr int Dd = 25;           // MAX_DISP + 1
constexpr int HW = Hh * Ww;      // 12288 (channel stride)
constexpr int BSTRIDE = 2 * Cc * HW;  // batch stride in floats
constexpr int CPR = 4;           // channels staged per round
constexpr int NR = Cc / CPR;     // 64 rounds
constexpr int ROWP = 24 + Ww;    // LDS row: 24-zero left pad + 192 data
constexpr int HT = 4;            // output rows per block
constexpr int RT = HT + 2;       // corr rows computed per block (halo above/below)
constexpr int TW = Ww + 4;       // box tile row: [0,1]=left zero pad, [2..193]=w, [194,195]=right pad
constexpr int NTHREADS = RT * 96;  // 576 threads = 9 waves

// Fused kernel: corr (over 256 channels, 25 disparities) + 3x3 all-ones box
// filter, no workspace. Block covers RT=6 corr rows (4 output + 2 halo),
// each lane owns (row r, w0=2u, w0+1) and 25 float2 accumulators.
__global__ __launch_bounds__(NTHREADS) void fused_kernel(const float* __restrict__ in,
                                                         float* __restrict__ out) {
  const int t  = threadIdx.x;
  const int r  = t / 96;          // 0..5 (corr row within block)
  const int u  = t % 96;
  const int w0 = 2 * u;

  // XCD-aware decode: adjacent h-tiles of the same b land on the same XCD
  // (default xcd = lin % 8 round-robin), so halo rows re-hit that XCD's L2.
  const int lin  = blockIdx.x;    // 0..255
  const int slot = lin & 7;
  const int jj   = lin >> 3;      // 0..31
  const int b    = slot + 8 * (jj >> 4);
  const int tile = jj & 15;
  const int hbase = tile * HT;
  const int h = hbase + r - 1;    // corr row in [-1, 64]
  const bool hvalid = (h >= 0) && (h < Hh);
  const int hc = hvalid ? h : 0;  // clamped for safe address arithmetic

  // LDS reused across phases: staging buffer (5184 floats) then box tile (1176).
  __shared__ float lds[RT * CPR * ROWP];
  auto x2s   = (float (*)[CPR][ROWP])lds;
  auto tilep = (float (*)[TW])lds;

  // Zero the 24-float left pads once: RT*CPR*24 = 576 writes = blockDim exactly.
  {
    const int rr  = t / (CPR * 24);
    const int rem = t % (CPR * 24);
    x2s[rr][rem / 24][rem % 24] = 0.0f;
  }

  const float* x1p = in + (size_t)b * BSTRIDE + (size_t)hc * Ww + w0;
  const float* x2p = x1p + (size_t)Cc * HW;

  float2 acc[Dd];
#pragma unroll
  for (int d = 0; d < Dd; ++d) acc[d] = make_float2(0.0f, 0.0f);

  // Prefetch round 0 (invalid halo rows contribute zeros => zero-padded conv in h)
  float2 px1[CPR], px2[CPR];
#pragma unroll
  for (int c = 0; c < CPR; ++c) {
    if (hvalid) {
      px1[c] = *(const float2*)(x1p + c * HW);
      px2[c] = *(const float2*)(x2p + c * HW);
    } else {
      px1[c] = make_float2(0.0f, 0.0f);
      px2[c] = make_float2(0.0f, 0.0f);
    }
  }

  for (int rnd = 0; rnd < NR; ++rnd) {
    __syncthreads();  // previous round finished reading LDS (also covers pad init)
    float2 cx1[CPR];
#pragma unroll
    for (int c = 0; c < CPR; ++c) {
      cx1[c] = px1[c];
      *(float2*)&x2s[r][c][24 + w0] = px2[c];
    }
    __syncthreads();  // staging visible

    // Issue next round's global loads AFTER the barrier so the barrier's
    // vmcnt(0) drain doesn't serialize them; compute below hides latency.
    if (rnd + 1 < NR && hvalid) {
      const float* p1 = x1p + (size_t)(rnd + 1) * CPR * HW;
      const float* p2 = p1 + (size_t)Cc * HW;
#pragma unroll
      for (int c = 0; c < CPR; ++c) {
        px1[c] = *(const float2*)(p1 + c * HW);
        px2[c] = *(const float2*)(p2 + c * HW);
      }
    }

#pragma unroll
    for (int c = 0; c < CPR; ++c) {
      // Sliding window x2[w0-24 .. w0+1] via 13 aligned ds_read_b64
      float win[26];
#pragma unroll
      for (int k = 0; k < 13; ++k) {
        const float2 v = *(const float2*)&x2s[r][c][w0 + 2 * k];
        win[2 * k]     = v.x;
        win[2 * k + 1] = v.y;
      }
      const float a0 = cx1[c].x, a1 = cx1[c].y;
#pragma unroll
      for (int d = 0; d < Dd; ++d) {
        acc[d].x = fmaf(a0, win[24 - d], acc[d].x);
        acc[d].y = fmaf(a1, win[25 - d], acc[d].y);
      }
    }
  }

  // ---- box-filter phase: per d, stage 6x192 corr rows in LDS, 3x3 sum ----
  float* outb = out + (size_t)b * Dd * Hh * Ww;
#pragma unroll
  for (int d = 0; d < Dd; ++d) {
    __syncthreads();  // prior LDS reads (accum phase or previous d) done
    *(float2*)&tilep[r][2 + w0] = acc[d];
    if (u == 0)  { tilep[r][0]      = 0.0f; tilep[r][1]      = 0.0f; }
    if (u == 95) { tilep[r][TW - 2] = 0.0f; tilep[r][TW - 1] = 0.0f; }
    __syncthreads();
    if (r < HT) {
      // output row hbase+r needs corr rows (tile rows) r, r+1, r+2
      float sx = 0.0f, sy = 0.0f;
#pragma unroll
      for (int q = 0; q < 3; ++q) {
        const float* trow = tilep[r + q];
        const float2 A = *(const float2*)&trow[w0];       // cols w0-2, w0-1
        const float2 B = *(const float2*)&trow[w0 + 2];   // cols w0,   w0+1
        const float2 C = *(const float2*)&trow[w0 + 4];   // cols w0+2, w0+3
        sx += A.y + B.x + B.y;
        sy += B.x + B.y + C.x;
      }
      *(float2*)(outb + ((size_t)d * Hh + hbase + r) * Ww + w0) = make_float2(sx, sy);
    }
  }
}

extern "C" void kernel_launch(void* const* d_in, const int* in_sizes, int n_in,
                              void* d_out, int out_size, void* d_ws, size_t ws_size,
                              hipStream_t stream) {
  const float* in = (const float*)d_in[0];
  float* out = (float*)d_out;
  (void)d_ws; (void)ws_size;  // workspace intentionally unused (no poison dependency)

  fused_kernel<<<dim3(Bq * (Hh / HT)), dim3(NTHREADS), 0, stream>>>(in, out);
}